// Round 11
// baseline (262.084 us; speedup 1.0000x reference)
//
#include <hip/hip_runtime.h>

typedef __bf16 bf16;
typedef __bf16 v8bf __attribute__((ext_vector_type(8)));
typedef float  v4f  __attribute__((ext_vector_type(4)));
typedef short  short4v __attribute__((ext_vector_type(4)));

__device__ __forceinline__ float sigf(float x){ return 1.0f/(1.0f + __expf(-x)); }

// async global -> LDS, 16B per lane (lds dest = wave-uniform base + lane*16)
typedef __attribute__((address_space(3))) unsigned int lds_u32;
typedef __attribute__((address_space(1))) const unsigned int gbl_u32;
__device__ __forceinline__ void gl16(const void* g, void* l) {
  __builtin_amdgcn_global_load_lds((gbl_u32*)g, (lds_u32*)l, 16, 0, 0);
}

// ---------------------------------------------------------------- prep bodies
struct WTab {
  const float* src[14];
  bf16* dst[14];
  int K[14], N[14], boff[14];
};

__device__ __forceinline__ void prepw_body(int bid, char* smem, const WTab& tab) {
  float (*lds)[33] = (float(*)[33])smem;
  int e = 0;
  #pragma unroll
  for (int i = 1; i < 14; i++) if (tab.boff[i] <= bid) e = i;
  int local = bid - tab.boff[e];
  int K = tab.K[e], N = tab.N[e];
  int nKT = K >> 5;
  int kt = local % nKT, nt = local / nKT;
  int k0 = kt * 32, n0 = nt * 32;
  const float* src = tab.src[e];
  bf16* dst = tab.dst[e];
  int tx = threadIdx.x & 31, ty = threadIdx.x >> 5;
  #pragma unroll
  for (int i = 0; i < 4; i++)
    lds[ty + i*8][tx] = src[(long)(k0 + ty + i*8) * N + n0 + tx];
  __syncthreads();
  #pragma unroll
  for (int i = 0; i < 4; i++)
    dst[(long)(n0 + ty + i*8) * K + k0 + tx] = (bf16)lds[tx][ty + i*8];
}

__device__ __forceinline__ void ln_a_body(int row, const float* __restrict__ a,
                                          float* __restrict__ out) {
  const float* x = a + (long)row * 768;
  int t = threadIdx.x;
  float lv[3], s = 0.f, q = 0.f;
  #pragma unroll
  for (int i = 0; i < 3; i++){ lv[i] = x[t + i*256]; s += lv[i]; q += lv[i]*lv[i]; }
  #pragma unroll
  for (int m = 1; m < 64; m <<= 1){ s += __shfl_xor(s, m); q += __shfl_xor(q, m); }
  __shared__ float ls[4], lq[4];
  int w = t >> 6, lane = t & 63;
  if (!lane){ ls[w] = s; lq[w] = q; }
  __syncthreads();
  s = ls[0]+ls[1]+ls[2]+ls[3]; q = lq[0]+lq[1]+lq[2]+lq[3];
  float mean = s * (1.f/768.f);
  float var  = q * (1.f/768.f) - mean*mean;
  float inv  = rsqrtf(var + 1e-5f);
  float* o = out + (long)row * 768;
  #pragma unroll
  for (int i = 0; i < 3; i++) o[t + i*256] = (lv[i] - mean) * inv;
}

// 256 threads handle TWO s-rows (sub = t>>7), 128 threads per row
__device__ __forceinline__ void ln_s_body(int rowpair, const float* __restrict__ sIn,
    const float* __restrict__ g1, const float* __restrict__ g2,
    bf16* __restrict__ s1, bf16* __restrict__ s2, bf16* __restrict__ sb) {
  int t = threadIdx.x & 127;
  int sub = threadIdx.x >> 7;
  int r = rowpair*2 + sub;
  const float* x = sIn + (long)r * 384;
  float lv[3], s = 0.f, q = 0.f;
  #pragma unroll
  for (int i = 0; i < 3; i++){ lv[i] = x[t + i*128]; s += lv[i]; q += lv[i]*lv[i]; }
  #pragma unroll
  for (int m = 1; m < 64; m <<= 1){ s += __shfl_xor(s, m); q += __shfl_xor(q, m); }
  __shared__ float ls[2][2], lq[2][2];
  int w = (t >> 6) & 1, lane = t & 63;
  if (!lane){ ls[sub][w] = s; lq[sub][w] = q; }
  __syncthreads();
  s = ls[sub][0] + ls[sub][1]; q = lq[sub][0] + lq[sub][1];
  float mean = s * (1.f/384.f);
  float var  = q * (1.f/384.f) - mean*mean;
  float inv  = rsqrtf(var + 1e-5f);
  long base = (long)r * 384;
  #pragma unroll
  for (int i = 0; i < 3; i++){
    int c = t + i*128;
    float y = (lv[i] - mean) * inv;
    s1[base + c] = (bf16)(y * g1[c]);
    s2[base + c] = (bf16)(y * g2[c]);
    sb[base + c] = (bf16)lv[i];
  }
}

// one launch: prepw (boffTot) + prepz (8) + ln_a (1024) + ln_s (512)
__global__ __launch_bounds__(256) void k_prep(WTab tab, int boffTot,
    const float* Wz, const float* gz, bf16* wzT,
    const float* A_in, float* alnr,
    const float* S_in, const float* g1, const float* g2,
    bf16* sl1, bf16* sl2, bf16* sbf)
{
  __shared__ __align__(16) char smem[4224];
  int bid = blockIdx.x;
  if (bid < boffTot) { prepw_body(bid, smem, tab); return; }
  bid -= boffTot;
  if (bid < 8) {
    int t = bid * 256 + threadIdx.x;
    int k = t >> 4, h = t & 15;
    wzT[h * 128 + k] = (bf16)(Wz[t] * gz[k]);
    return;
  }
  bid -= 8;
  if (bid < 1024) { ln_a_body(bid, A_in, alnr); return; }
  bid -= 1024;
  ln_s_body(bid, S_in, g1, g2, sl1, sl2, sbf);
}

// ------------------------------------------------- z LN + proj via MFMA (body)
__device__ __forceinline__ void zbias_body(int bid, char* smem,
    const float* __restrict__ z, const bf16* __restrict__ wzT,
    bf16* __restrict__ biasb) {
  float (*pb)[17] = (float(*)[17])smem;
  int t = threadIdx.x, lane = t & 63, w = t >> 6;
  int r16 = lane & 15, g4 = lane >> 4;
  long base = (long)bid * 64;
  long pos = base + w*16 + r16;
  const float* zr = z + pos * 128;
  float4 xv[8];
  #pragma unroll
  for (int s = 0; s < 4; s++) {
    xv[2*s]   = *reinterpret_cast<const float4*>(&zr[s*32 + g4*8]);
    xv[2*s+1] = *reinterpret_cast<const float4*>(&zr[s*32 + g4*8 + 4]);
  }
  const float* x = reinterpret_cast<const float*>(xv);
  float sm = 0.f, q = 0.f;
  #pragma unroll
  for (int i = 0; i < 32; i++){ sm += x[i]; q += x[i]*x[i]; }
  sm += __shfl_xor(sm, 16); q += __shfl_xor(q, 16);
  sm += __shfl_xor(sm, 32); q += __shfl_xor(q, 32);
  float mean = sm * (1.f/128.f), var = q * (1.f/128.f) - mean*mean;
  float inv = rsqrtf(var + 1e-5f);
  v4f acc = (v4f){0.f, 0.f, 0.f, 0.f};
  #pragma unroll
  for (int s = 0; s < 4; s++) {
    union { bf16 b[8]; v8bf v; } ua;
    #pragma unroll
    for (int j = 0; j < 8; j++) ua.b[j] = (bf16)((x[s*8 + j] - mean) * inv);
    v8bf bw = *reinterpret_cast<const v8bf*>(&wzT[r16*128 + s*32 + g4*8]);
    acc = __builtin_amdgcn_mfma_f32_16x16x32_bf16(ua.v, bw, acc, 0, 0, 0);
  }
  #pragma unroll
  for (int r = 0; r < 4; r++) pb[w*16 + g4*4 + r][r16] = acc[r];
  __syncthreads();
  int p = t & 63, hb = t >> 6;
  #pragma unroll
  for (int j = 0; j < 4; j++) {
    int h = hb*4 + j;
    biasb[((long)h << 20) + base + p] = (bf16)pb[p][h];
  }
}

// ---------------------------------------------------------------- GEMM body
#define EPI_ADASG  0
#define EPI_SWIGLU 1
#define EPI_QKVG   2
#define EPI_WO     6
#define EPI_WB     7

template<int TM, int TN, bool DUAL, int EPI>
__device__ __forceinline__ void gemm_body(
    bf16* As, bf16* Bs, int m0, int n0, int z,
    const bf16* __restrict__ Ap, const bf16* __restrict__ B1, long sBpair, int K,
    const float* __restrict__ f0, const float* __restrict__ f1,
    const float* __restrict__ f2, const float* __restrict__ f3,
    const float* __restrict__ f4, const bf16* __restrict__ bb0,
    void* __restrict__ outp, long sOutz)
{
  constexpr int WM = TM/2, WN = TN/2;
  constexpr int MI = WM/16, NI = WN/16;
  const bf16* B2 = B1 + sBpair;
  int t = threadIdx.x, lane = t & 63, w = t >> 6;
  int wr = w >> 1, wc = w & 1;
  int r16 = lane & 15, g4 = lane >> 4;
  constexpr int NACC = DUAL ? 2 : 1;
  v4f acc[NACC][MI][NI];
  #pragma unroll
  for (int d = 0; d < NACC; d++)
    #pragma unroll
    for (int mi = 0; mi < MI; mi++)
      #pragma unroll
      for (int ni = 0; ni < NI; ni++)
        acc[d][mi][ni] = (v4f){0.f, 0.f, 0.f, 0.f};

  for (int k0 = 0; k0 < K; k0 += 64) {
    #pragma unroll
    for (int cb = 0; cb < TM/32; cb++) {
      int cc = cb*4 + w;
      int c16 = cc*64 + lane;
      int row = c16 >> 3, col = c16 & 7;
      int scol = col ^ (row & 7);
      gl16(&Ap[(long)(m0 + row)*K + k0 + scol*8], (char*)As + cc*1024);
    }
    #pragma unroll
    for (int cb = 0; cb < TN/32; cb++) {
      int cc = cb*4 + w;
      int c16 = cc*64 + lane;
      int row = c16 >> 3, col = c16 & 7;
      int scol = col ^ (row & 7);
      gl16(&B1[(long)(n0 + row)*K + k0 + scol*8], (char*)Bs + cc*1024);
      if constexpr (DUAL)
        gl16(&B2[(long)(n0 + row)*K + k0 + scol*8], (char*)Bs + TN*128 + cc*1024);
    }
    __syncthreads();
    #pragma unroll
    for (int s = 0; s < 2; s++) {
      int ch = s*4 + g4;
      v8bf af[MI];
      #pragma unroll
      for (int mi = 0; mi < MI; mi++) {
        int ra = wr*WM + mi*16 + r16;
        af[mi] = *reinterpret_cast<const v8bf*>(
            (const char*)As + ra*128 + ((ch ^ (ra & 7)) << 4));
      }
      #pragma unroll
      for (int d = 0; d < NACC; d++)
        #pragma unroll
        for (int ni = 0; ni < NI; ni++) {
          int rb = wc*WN + ni*16 + r16;
          v8bf bfv = *reinterpret_cast<const v8bf*>(
              (const char*)Bs + d*(TN*128) + rb*128 + ((ch ^ (rb & 7)) << 4));
          #pragma unroll
          for (int mi = 0; mi < MI; mi++)
            acc[d][mi][ni] = __builtin_amdgcn_mfma_f32_16x16x32_bf16(af[mi], bfv, acc[d][mi][ni], 0, 0, 0);
        }
    }
    __syncthreads();
  }

  int colb = n0 + wc*WN + r16;
  int rowb = m0 + wr*WM + (g4 << 2);
  #pragma unroll
  for (int mi = 0; mi < MI; mi++)
    #pragma unroll
    for (int ni = 0; ni < NI; ni++) {
      int col = colb + ni*16;
      if constexpr (EPI == EPI_ADASG) {
        if (z < 2) {
          float bg = (z == 0 ? f1 : f2)[col];
          bf16* o = (bf16*)outp + (long)z * sOutz;
          #pragma unroll
          for (int r = 0; r < 4; r++) {
            long idx = (long)(rowb + mi*16 + r)*768 + col;
            float gl = acc[0][mi][ni][r] + bg;
            o[idx] = (bf16)(sigf(gl) * f0[idx] + acc[1][mi][ni][r]);
          }
        } else {
          bf16* o0 = (bf16*)outp + 2*sOutz;
          bf16* o1 = (bf16*)outp + 3*sOutz;
          #pragma unroll
          for (int r = 0; r < 4; r++) {
            long idx = (long)(rowb + mi*16 + r)*768 + col;
            o0[idx] = (bf16)sigf(acc[0][mi][ni][r] + f3[col]);
            o1[idx] = (bf16)sigf(acc[1][mi][ni][r] + f4[col]);
          }
        }
      } else if constexpr (EPI == EPI_SWIGLU) {
        bf16* o = (bf16*)outp;
        #pragma unroll
        for (int r = 0; r < 4; r++) {
          long idx = (long)(rowb + mi*16 + r)*1536 + col;
          float x1 = acc[0][mi][ni][r], x2 = acc[1][mi][ni][r];
          o[idx] = (bf16)(x1 * sigf(x1) * x2);
        }
      } else if constexpr (EPI == EPI_QKVG) {
        int h = col / 48, d = col - h*48;
        if (z == 0) {
          const float qs = 0.14433756729740643f;
          bf16* qp = (bf16*)outp;
          #pragma unroll
          for (int r = 0; r < 4; r++)
            qp[(long)h*65536 + (long)(rowb + mi*16 + r)*64 + d] =
              (bf16)((acc[0][mi][ni][r] + f0[col]) * qs);
        } else if (z == 1) {
          bf16* kp = (bf16*)outp + sOutz;
          #pragma unroll
          for (int r = 0; r < 4; r++)
            kp[(long)h*65536 + (long)(rowb + mi*16 + r)*64 + d] = (bf16)acc[0][mi][ni][r];
        } else if (z == 2) {
          bf16* vT = (bf16*)outp + 2*sOutz;
          union { bf16 h4[4]; short4v s4; } u;
          #pragma unroll
          for (int r = 0; r < 4; r++) u.h4[r] = (bf16)acc[0][mi][ni][r];
          *reinterpret_cast<short4v*>(&vT[(long)h*65536 + (long)d*1024 + rowb + mi*16]) = u.s4;
        } else {
          bf16* gp = (bf16*)outp + 3*sOutz;
          #pragma unroll
          for (int r = 0; r < 4; r++)
            gp[(long)(rowb + mi*16 + r)*768 + col] = (bf16)sigf(acc[0][mi][ni][r] + f1[col]);
        }
      } else if constexpr (EPI == EPI_WO) {
        float* o = (float*)outp;
        #pragma unroll
        for (int r = 0; r < 4; r++) {
          long idx = (long)(rowb + mi*16 + r)*768 + col;
          o[idx] = o[idx] + (float)bb0[idx] * (acc[0][mi][ni][r] + f0[col]);
        }
      } else {  // EPI_WB: OUT = sgf1*acc
        float* o = (float*)outp;
        #pragma unroll
        for (int r = 0; r < 4; r++) {
          long idx = (long)(rowb + mi*16 + r)*768 + col;
          o[idx] = (float)bb0[idx] * acc[0][mi][ni][r];
        }
      }
    }
}

template<int TM, int TN, bool DUAL, int EPI>
__global__ __launch_bounds__(256) void gemm_k(
    const bf16* A, const bf16* B, long sAz, long sBz, long sBpair, int K,
    const float* f0, const float* f1, const float* f2, const float* f3,
    const float* f4, const bf16* bb0, void* outp, long sOutz)
{
  __shared__ __align__(16) bf16 As[TM*64];
  __shared__ __align__(16) bf16 Bs[(DUAL?2:1)*TN*64];
  int z = blockIdx.z;
  gemm_body<TM,TN,DUAL,EPI>(As, Bs, blockIdx.y*TM, blockIdx.x*TN, z,
      A + (long)z*sAz, B + (long)z*sBz, sBpair, K,
      f0, f1, f2, f3, f4, bb0, outp, sOutz);
}

#define ZSPLIT 5120

// ---------------------------------------------------------------- mega A
// adaLN+gates GEMM (576 blocks, first) ∥ zbias[0..ZSPLIT)
__global__ __launch_bounds__(256, 4) void k_mega_a(
    const bf16* sl1, const bf16* wGA6, const float* alnr,
    const float* bg1, const float* bg2, const float* bsL, const float* b_t,
    bf16* aln, const float* Zin, const bf16* wzT, bf16* biasb)
{
  __shared__ __align__(16) char smem[24576];
  int bid = blockIdx.x;
  if (bid < 576) {
    int z = bid / 192, rem = bid % 192;
    gemm_body<64,64,true,EPI_ADASG>((bf16*)smem, (bf16*)(smem + 8192),
        (rem/12)*64, (rem%12)*64, z,
        sl1 + (long)z*393216, wGA6 + (long)z*589824, 294912, 384,
        alnr, bg1, bg2, bsL, b_t, nullptr, aln, 786432);
  } else {
    zbias_body(bid - 576, smem, Zin, wzT, biasb);
  }
}

// ---------------------------------------------------------------- mega B
// QKVG 128x128 (192, first) ∥ SwiGLU 64x64 dual (384) ∥ zbias[ZSPLIT..16384)
__global__ __launch_bounds__(256, 3) void k_mega_b(
    const bf16* aln, const bf16* wQKVG, const float* bq, const float* bgate,
    bf16* qkv, const bf16* a2b, const bf16* wW12, bf16* bmid,
    const float* Zin, const bf16* wzT, bf16* biasb)
{
  __shared__ __align__(16) char smem[32768];
  int bid = blockIdx.x;
  if (bid < 192) {
    int z = bid / 48, rem = bid % 48;
    gemm_body<128,128,false,EPI_QKVG>((bf16*)smem, (bf16*)(smem + 16384),
        (rem/6)*128, (rem%6)*128, z,
        aln, wQKVG + (long)z*589824, 0, 768,
        bq, bgate, nullptr, nullptr, nullptr, nullptr, qkv, 1048576);
  } else if (bid < 576) {
    int rem = bid - 192;
    gemm_body<64,64,true,EPI_SWIGLU>((bf16*)smem, (bf16*)(smem + 8192),
        (rem/24)*64, (rem%24)*64, 0,
        a2b, wW12, 1179648, 768,
        nullptr, nullptr, nullptr, nullptr, nullptr, nullptr, bmid, 0);
  } else {
    zbias_body(bid - 576 + ZSPLIT, smem, Zin, wzT, biasb);
  }
}

// ---------------------------------------------------------------- flash body
__device__ __forceinline__ void flash_body(int qt, int h, char* smem,
    const bf16* __restrict__ qp, const bf16* __restrict__ kp,
    const bf16* __restrict__ vT, const bf16* __restrict__ biasb,
    const bf16* __restrict__ gp, bf16* __restrict__ gob)
{
  int t = threadIdx.x, lane = t & 63, w = t >> 6;
  int q0 = qt * 64 + w * 16;
  int r16 = lane & 15, g4 = lane >> 4;
  bf16* plw = (bf16*)smem + w * 1152;
  const bf16* qb = qp + ((long)h << 16);
  const bf16* kb = kp + ((long)h << 16);
  const bf16* vb = vT + ((long)h << 16);
  const bf16* bb = biasb + ((long)h << 20) + (long)q0 * 1024;

  v8bf qa[2];
  #pragma unroll
  for (int s = 0; s < 2; s++)
    qa[s] = *reinterpret_cast<const v8bf*>(&qb[(long)(q0 + r16)*64 + s*32 + g4*8]);

  v4f oacc[4];
  #pragma unroll
  for (int nd = 0; nd < 4; nd++) oacc[nd] = (v4f){0.f, 0.f, 0.f, 0.f};
  float mrun[4], lrun[4];
  #pragma unroll
  for (int r = 0; r < 4; r++){ mrun[r] = -1e30f; lrun[r] = 0.f; }

  for (int kt = 0; kt < 16; kt++) {
    int k0 = kt * 64;
    v4f sacc[4];
    #pragma unroll
    for (int nk = 0; nk < 4; nk++) sacc[nk] = (v4f){0.f, 0.f, 0.f, 0.f};
    #pragma unroll
    for (int nk = 0; nk < 4; nk++)
      #pragma unroll
      for (int s = 0; s < 2; s++) {
        v8bf kf = *reinterpret_cast<const v8bf*>(&kb[(long)(k0 + nk*16 + r16)*64 + s*32 + g4*8]);
        sacc[nk] = __builtin_amdgcn_mfma_f32_16x16x32_bf16(qa[s], kf, sacc[nk], 0, 0, 0);
      }
    float mtile[4];
    #pragma unroll
    for (int r = 0; r < 4; r++) mtile[r] = -1e30f;
    #pragma unroll
    for (int nk = 0; nk < 4; nk++)
      #pragma unroll
      for (int r = 0; r < 4; r++) {
        float bvv = (float)bb[(long)(g4*4 + r)*1024 + k0 + nk*16 + r16];
        sacc[nk][r] += bvv;
        mtile[r] = fmaxf(mtile[r], sacc[nk][r]);
      }
    #pragma unroll
    for (int r = 0; r < 4; r++) {
      #pragma unroll
      for (int m = 1; m < 16; m <<= 1) mtile[r] = fmaxf(mtile[r], __shfl_xor(mtile[r], m));
    }
    float scl[4], rsum[4];
    #pragma unroll
    for (int r = 0; r < 4; r++) {
      float mn = fmaxf(mrun[r], mtile[r]);
      scl[r] = __expf(mrun[r] - mn);
      mrun[r] = mn;
      rsum[r] = 0.f;
    }
    #pragma unroll
    for (int nk = 0; nk < 4; nk++)
      #pragma unroll
      for (int r = 0; r < 4; r++) {
        float p = __expf(sacc[nk][r] - mrun[r]);
        rsum[r] += p;
        plw[(g4*4 + r)*72 + nk*16 + r16] = (bf16)p;
      }
    #pragma unroll
    for (int r = 0; r < 4; r++) {
      #pragma unroll
      for (int m = 1; m < 16; m <<= 1) rsum[r] += __shfl_xor(rsum[r], m);
      lrun[r] = lrun[r]*scl[r] + rsum[r];
      #pragma unroll
      for (int nd = 0; nd < 4; nd++) oacc[nd][r] *= scl[r];
    }
    v8bf pa[2];
    #pragma unroll
    for (int s = 0; s < 2; s++)
      pa[s] = *reinterpret_cast<const v8bf*>(&plw[r16*72 + s*32 + g4*8]);
    #pragma unroll
    for (int nd = 0; nd < 4; nd++)
      #pragma unroll
      for (int s = 0; s < 2; s++) {
        v8bf vf = *reinterpret_cast<const v8bf*>(&vb[(long)(nd*16 + r16)*1024 + k0 + s*32 + g4*8]);
        oacc[nd] = __builtin_amdgcn_mfma_f32_16x16x32_bf16(pa[s], vf, oacc[nd], 0, 0, 0);
      }
  }
  #pragma unroll
  for (int r = 0; r < 4; r++) {
    int qrow = q0 + g4*4 + r;
    float invl = 1.0f / lrun[r];
    #pragma unroll
    for (int nd = 0; nd < 3; nd++) {
      long idx = (long)qrow*768 + h*48 + nd*16 + r16;
      gob[idx] = (bf16)(oacc[nd][r] * invl * (float)gp[idx]);
    }
  }
}

// ---------------------------------------------------------------- tail kernel
// WB GEMM (192 blocks, first: OUT = sgf1*(bmid@WbT)) ∥ flash (256 blocks)
__global__ __launch_bounds__(256) void k_tail(
    const bf16* bmid, const bf16* wWbT, const bf16* sgf1, float* OUT,
    const bf16* qp, const bf16* kp, const bf16* vT, const bf16* biasb,
    const bf16* gp, bf16* gob)
{
  __shared__ __align__(16) char smem[16384];
  int bid = blockIdx.x;
  if (bid < 192) {
    gemm_body<64,64,false,EPI_WB>((bf16*)smem, (bf16*)(smem + 8192),
        (bid/12)*64, (bid%12)*64, 0,
        bmid, wWbT, 0, 1536,
        nullptr, nullptr, nullptr, nullptr, nullptr, sgf1, OUT, 0);
  } else {
    int local = bid - 192;
    flash_body(local & 15, local >> 4, smem, qp, kp, vT, biasb, gp, gob);
  }
}

// ---------------------------------------------------------------- launcher
extern "C" void kernel_launch(void* const* d_in, const int* in_sizes, int n_in,
                              void* d_out, int out_size, void* d_ws, size_t ws_size,
                              hipStream_t stream)
{
  const float* A_in  = (const float*)d_in[0];
  const float* S_in  = (const float*)d_in[1];
  const float* Z_in  = (const float*)d_in[2];
  const float* g_s1  = (const float*)d_in[3];
  const float* Wg1   = (const float*)d_in[4];
  const float* bg1   = (const float*)d_in[5];
  const float* Wadd1 = (const float*)d_in[6];
  const float* g_z   = (const float*)d_in[7];
  const float* Wz    = (const float*)d_in[8];
  const float* Wq    = (const float*)d_in[9];
  const float* bq    = (const float*)d_in[10];
  const float* Wk    = (const float*)d_in[11];
  const float* Wv    = (const float*)d_in[12];
  const float* Wgate = (const float*)d_in[13];
  const float* bgate = (const float*)d_in[14];
  const float* Wo    = (const float*)d_in[15];
  const float* bo    = (const float*)d_in[16];
  const float* WsL   = (const float*)d_in[17];
  const float* bsL   = (const float*)d_in[18];
  const float* g_s2  = (const float*)d_in[19];
  const float* Wg2   = (const float*)d_in[20];
  const float* bg2   = (const float*)d_in[21];
  const float* Wadd2 = (const float*)d_in[22];
  const float* W1    = (const float*)d_in[23];
  const float* W2    = (const float*)d_in[24];
  const float* Wb    = (const float*)d_in[25];
  const float* WsT   = (const float*)d_in[26];
  const float* b_t   = (const float*)d_in[27];
  float* OUT = (float*)d_out;

  char* ws = (char*)d_ws;
  size_t off = 0;
  auto alloc = [&](size_t bytes) -> void* {
    void* p = ws + off; off += (bytes + 255) & ~(size_t)255; return p; };

  bf16*  wGA6  = (bf16*) alloc(6ul*294912*2);   // Wg1T,Wadd1T,Wg2T,Wadd2T,WsLT,WsTT
  bf16*  wQKVG = (bf16*) alloc(4ul*589824*2);   // WqT,WkT,WvT,WgateT
  bf16*  wWoT  = (bf16*) alloc(589824ul*2);
  bf16*  wW12  = (bf16*) alloc(2ul*1179648*2);  // W1T, W2T
  bf16*  wWbT  = (bf16*) alloc(1179648ul*2);
  bf16*  wzT   = (bf16*) alloc(2048ul*2);       // [16][128] gz-folded
  bf16*  sl1   = (bf16*) alloc(393216ul*2);     // sl1,sl2,sbf contiguous
  bf16*  sl2   = (bf16*) alloc(393216ul*2);
  bf16*  sbf   = (bf16*) alloc(393216ul*2);
  float* alnr  = (float*)alloc(786432ul*4);
  bf16*  aln   = (bf16*) alloc(786432ul*2);     // aln,a2b,sgf0,sgf1 contiguous
  bf16*  a2b   = (bf16*) alloc(786432ul*2);
  bf16*  sgf   = (bf16*) alloc(2ul*786432*2);
  bf16*  qkv   = (bf16*) alloc((3ul*1048576 + 786432)*2);  // qp,kp,vT,gp
  bf16*  biasb = (bf16*) alloc(16777216ul*2);
  bf16*  gob   = (bf16*) alloc(786432ul*2);
  bf16*  bmid  = (bf16*) alloc(1572864ul*2);

  WTab tab;
  auto setw = [&](int i, const float* src, bf16* dst, int K, int N){
    tab.src[i] = src; tab.dst[i] = dst; tab.K[i] = K; tab.N[i] = N; };
  setw(0,  Wg1,   wGA6,             384,  768);
  setw(1,  Wadd1, wGA6 + 294912,    384,  768);
  setw(2,  Wg2,   wGA6 + 589824,    384,  768);
  setw(3,  Wadd2, wGA6 + 884736,    384,  768);
  setw(4,  WsL,   wGA6 + 1179648,   384,  768);
  setw(5,  WsT,   wGA6 + 1474560,   384,  768);
  setw(6,  Wq,    wQKVG,            768,  768);
  setw(7,  Wk,    wQKVG + 589824,   768,  768);
  setw(8,  Wv,    wQKVG + 2*589824, 768,  768);
  setw(9,  Wgate, wQKVG + 3*589824, 768,  768);
  setw(10, Wo,    wWoT,             768,  768);
  setw(11, W1,    wW12,             768, 1536);
  setw(12, W2,    wW12 + 1179648,   768, 1536);
  setw(13, Wb,    wWbT,            1536,  768);
  int boff = 0;
  for (int i = 0; i < 14; i++){ tab.boff[i] = boff; boff += (tab.K[i]/32)*(tab.N[i]/32); }

  (void)hipMemsetAsync(qkv, 0, 3ul*1048576*2, stream);  // zero q,k,vT pads

  // prepw + prepz + ln_a + ln_s in one launch
  k_prep<<<boff + 8 + 1024 + 512, 256, 0, stream>>>(
      tab, boff, Wz, g_z, wzT, A_in, alnr, S_in, g_s1, g_s2, sl1, sl2, sbf);

  // adaLN+gates ∥ zbias[0..ZSPLIT)
  k_mega_a<<<576 + ZSPLIT, 256, 0, stream>>>(
      sl1, wGA6, alnr, bg1, bg2, bsL, b_t, aln, Z_in, wzT, biasb);

  // QKVG(128²) ∥ SwiGLU ∥ zbias[ZSPLIT..16384)
  k_mega_b<<<576 + (16384 - ZSPLIT), 256, 0, stream>>>(
      aln, wQKVG, bq, bgate, qkv, a2b, wW12, bmid, Z_in, wzT, biasb);

  // WB(OUT = sgf1*(bmid@WbT)) ∥ flash
  k_tail<<<448, 256, 0, stream>>>(
      bmid, wWbT, sgf + 786432, OUT,
      qkv, qkv + 1048576, qkv + 2097152, biasb, qkv + 3145728, gob);

  // OUT += sgf0 * (gob@WoT + bo)
  gemm_k<64,64,false,EPI_WO><<<dim3(12,16,1), 256, 0, stream>>>(
      gob, wWoT, 0, 0, 0, 768,
      bo, nullptr, nullptr, nullptr, nullptr, sgf, OUT, 0);
}

// Round 13
// 232.644 us; speedup vs baseline: 1.1265x; 1.1265x over previous
//
#include <hip/hip_runtime.h>

typedef __bf16 bf16;
typedef __bf16 v8bf __attribute__((ext_vector_type(8)));
typedef float  v4f  __attribute__((ext_vector_type(4)));
typedef short  short4v __attribute__((ext_vector_type(4)));

__device__ __forceinline__ float sigf(float x){ return 1.0f/(1.0f + __expf(-x)); }

// async global -> LDS, 16B per lane (lds dest = wave-uniform base + lane*16)
typedef __attribute__((address_space(3))) unsigned int lds_u32;
typedef __attribute__((address_space(1))) const unsigned int gbl_u32;
__device__ __forceinline__ void gl16(const void* g, void* l) {
  __builtin_amdgcn_global_load_lds((gbl_u32*)g, (lds_u32*)l, 16, 0, 0);
}

// ---------------------------------------------------------------- prep bodies
struct WTab {
  const float* src[14];
  bf16* dst[14];
  int K[14], N[14], boff[14];
};

__device__ __forceinline__ void prepw_body(int bid, char* smem, const WTab& tab) {
  float (*lds)[33] = (float(*)[33])smem;
  int e = 0;
  #pragma unroll
  for (int i = 1; i < 14; i++) if (tab.boff[i] <= bid) e = i;
  int local = bid - tab.boff[e];
  int K = tab.K[e], N = tab.N[e];
  int nKT = K >> 5;
  int kt = local % nKT, nt = local / nKT;
  int k0 = kt * 32, n0 = nt * 32;
  const float* src = tab.src[e];
  bf16* dst = tab.dst[e];
  int tx = threadIdx.x & 31, ty = threadIdx.x >> 5;
  #pragma unroll
  for (int i = 0; i < 4; i++)
    lds[ty + i*8][tx] = src[(long)(k0 + ty + i*8) * N + n0 + tx];
  __syncthreads();
  #pragma unroll
  for (int i = 0; i < 4; i++)
    dst[(long)(n0 + ty + i*8) * K + k0 + tx] = (bf16)lds[tx][ty + i*8];
}

__device__ __forceinline__ void ln_a_body(int row, const float* __restrict__ a,
                                          float* __restrict__ out) {
  const float* x = a + (long)row * 768;
  int t = threadIdx.x;
  float lv[3], s = 0.f, q = 0.f;
  #pragma unroll
  for (int i = 0; i < 3; i++){ lv[i] = x[t + i*256]; s += lv[i]; q += lv[i]*lv[i]; }
  #pragma unroll
  for (int m = 1; m < 64; m <<= 1){ s += __shfl_xor(s, m); q += __shfl_xor(q, m); }
  __shared__ float ls[4], lq[4];
  int w = t >> 6, lane = t & 63;
  if (!lane){ ls[w] = s; lq[w] = q; }
  __syncthreads();
  s = ls[0]+ls[1]+ls[2]+ls[3]; q = lq[0]+lq[1]+lq[2]+lq[3];
  float mean = s * (1.f/768.f);
  float var  = q * (1.f/768.f) - mean*mean;
  float inv  = rsqrtf(var + 1e-5f);
  float* o = out + (long)row * 768;
  #pragma unroll
  for (int i = 0; i < 3; i++) o[t + i*256] = (lv[i] - mean) * inv;
}

// 256 threads handle TWO s-rows (sub = t>>7), 128 threads per row
__device__ __forceinline__ void ln_s_body(int rowpair, const float* __restrict__ sIn,
    const float* __restrict__ g1, const float* __restrict__ g2,
    bf16* __restrict__ s1, bf16* __restrict__ s2, bf16* __restrict__ sb) {
  int t = threadIdx.x & 127;
  int sub = threadIdx.x >> 7;
  int r = rowpair*2 + sub;
  const float* x = sIn + (long)r * 384;
  float lv[3], s = 0.f, q = 0.f;
  #pragma unroll
  for (int i = 0; i < 3; i++){ lv[i] = x[t + i*128]; s += lv[i]; q += lv[i]*lv[i]; }
  #pragma unroll
  for (int m = 1; m < 64; m <<= 1){ s += __shfl_xor(s, m); q += __shfl_xor(q, m); }
  __shared__ float ls[2][2], lq[2][2];
  int w = (t >> 6) & 1, lane = t & 63;
  if (!lane){ ls[sub][w] = s; lq[sub][w] = q; }
  __syncthreads();
  s = ls[sub][0] + ls[sub][1]; q = lq[sub][0] + lq[sub][1];
  float mean = s * (1.f/384.f);
  float var  = q * (1.f/384.f) - mean*mean;
  float inv  = rsqrtf(var + 1e-5f);
  long base = (long)r * 384;
  #pragma unroll
  for (int i = 0; i < 3; i++){
    int c = t + i*128;
    float y = (lv[i] - mean) * inv;
    s1[base + c] = (bf16)(y * g1[c]);
    s2[base + c] = (bf16)(y * g2[c]);
    sb[base + c] = (bf16)lv[i];
  }
}

// one launch: prepw (boffTot) + prepz (8) + ln_a (1024) + ln_s (512)
__global__ __launch_bounds__(256) void k_prep(WTab tab, int boffTot,
    const float* Wz, const float* gz, bf16* wzT,
    const float* A_in, float* alnr,
    const float* S_in, const float* g1, const float* g2,
    bf16* sl1, bf16* sl2, bf16* sbf)
{
  __shared__ __align__(16) char smem[4224];
  int bid = blockIdx.x;
  if (bid < boffTot) { prepw_body(bid, smem, tab); return; }
  bid -= boffTot;
  if (bid < 8) {
    int t = bid * 256 + threadIdx.x;
    int k = t >> 4, h = t & 15;
    wzT[h * 128 + k] = (bf16)(Wz[t] * gz[k]);
    return;
  }
  bid -= 8;
  if (bid < 1024) { ln_a_body(bid, A_in, alnr); return; }
  bid -= 1024;
  ln_s_body(bid, S_in, g1, g2, sl1, sl2, sbf);
}

// ------------------------------------------------- z LN + proj via MFMA (body)
__device__ __forceinline__ void zbias_body(int bid, char* smem,
    const float* __restrict__ z, const bf16* __restrict__ wzT,
    bf16* __restrict__ biasb) {
  float (*pb)[17] = (float(*)[17])smem;
  int t = threadIdx.x, lane = t & 63, w = t >> 6;
  int r16 = lane & 15, g4 = lane >> 4;
  long base = (long)bid * 64;
  long pos = base + w*16 + r16;
  const float* zr = z + pos * 128;
  float4 xv[8];
  #pragma unroll
  for (int s = 0; s < 4; s++) {
    xv[2*s]   = *reinterpret_cast<const float4*>(&zr[s*32 + g4*8]);
    xv[2*s+1] = *reinterpret_cast<const float4*>(&zr[s*32 + g4*8 + 4]);
  }
  const float* x = reinterpret_cast<const float*>(xv);
  float sm = 0.f, q = 0.f;
  #pragma unroll
  for (int i = 0; i < 32; i++){ sm += x[i]; q += x[i]*x[i]; }
  sm += __shfl_xor(sm, 16); q += __shfl_xor(q, 16);
  sm += __shfl_xor(sm, 32); q += __shfl_xor(q, 32);
  float mean = sm * (1.f/128.f), var = q * (1.f/128.f) - mean*mean;
  float inv = rsqrtf(var + 1e-5f);
  v4f acc = (v4f){0.f, 0.f, 0.f, 0.f};
  #pragma unroll
  for (int s = 0; s < 4; s++) {
    union { bf16 b[8]; v8bf v; } ua;
    #pragma unroll
    for (int j = 0; j < 8; j++) ua.b[j] = (bf16)((x[s*8 + j] - mean) * inv);
    v8bf bw = *reinterpret_cast<const v8bf*>(&wzT[r16*128 + s*32 + g4*8]);
    acc = __builtin_amdgcn_mfma_f32_16x16x32_bf16(ua.v, bw, acc, 0, 0, 0);
  }
  #pragma unroll
  for (int r = 0; r < 4; r++) pb[w*16 + g4*4 + r][r16] = acc[r];
  __syncthreads();
  int p = t & 63, hb = t >> 6;
  #pragma unroll
  for (int j = 0; j < 4; j++) {
    int h = hb*4 + j;
    biasb[((long)h << 20) + base + p] = (bf16)pb[p][h];
  }
}

// ---------------------------------------------------------------- GEMM body
#define EPI_ADASG  0
#define EPI_SWIGLU 1
#define EPI_QKVG   2
#define EPI_WO     6
#define EPI_WB     7

template<int TM, int TN, bool DUAL, int EPI>
__device__ __forceinline__ void gemm_body(
    bf16* As, bf16* Bs, int m0, int n0, int z,
    const bf16* __restrict__ Ap, const bf16* __restrict__ B1, long sBpair, int K,
    const float* __restrict__ f0, const float* __restrict__ f1,
    const float* __restrict__ f2, const float* __restrict__ f3,
    const float* __restrict__ f4, const bf16* __restrict__ bb0,
    void* __restrict__ outp, long sOutz)
{
  constexpr int WM = TM/2, WN = TN/2;
  constexpr int MI = WM/16, NI = WN/16;
  const bf16* B2 = B1 + sBpair;
  int t = threadIdx.x, lane = t & 63, w = t >> 6;
  int wr = w >> 1, wc = w & 1;
  int r16 = lane & 15, g4 = lane >> 4;
  constexpr int NACC = DUAL ? 2 : 1;
  v4f acc[NACC][MI][NI];
  #pragma unroll
  for (int d = 0; d < NACC; d++)
    #pragma unroll
    for (int mi = 0; mi < MI; mi++)
      #pragma unroll
      for (int ni = 0; ni < NI; ni++)
        acc[d][mi][ni] = (v4f){0.f, 0.f, 0.f, 0.f};

  for (int k0 = 0; k0 < K; k0 += 64) {
    #pragma unroll
    for (int cb = 0; cb < TM/32; cb++) {
      int cc = cb*4 + w;
      int c16 = cc*64 + lane;
      int row = c16 >> 3, col = c16 & 7;
      int scol = col ^ (row & 7);
      gl16(&Ap[(long)(m0 + row)*K + k0 + scol*8], (char*)As + cc*1024);
    }
    #pragma unroll
    for (int cb = 0; cb < TN/32; cb++) {
      int cc = cb*4 + w;
      int c16 = cc*64 + lane;
      int row = c16 >> 3, col = c16 & 7;
      int scol = col ^ (row & 7);
      gl16(&B1[(long)(n0 + row)*K + k0 + scol*8], (char*)Bs + cc*1024);
      if constexpr (DUAL)
        gl16(&B2[(long)(n0 + row)*K + k0 + scol*8], (char*)Bs + TN*128 + cc*1024);
    }
    __syncthreads();
    #pragma unroll
    for (int s = 0; s < 2; s++) {
      int ch = s*4 + g4;
      v8bf af[MI];
      #pragma unroll
      for (int mi = 0; mi < MI; mi++) {
        int ra = wr*WM + mi*16 + r16;
        af[mi] = *reinterpret_cast<const v8bf*>(
            (const char*)As + ra*128 + ((ch ^ (ra & 7)) << 4));
      }
      #pragma unroll
      for (int d = 0; d < NACC; d++)
        #pragma unroll
        for (int ni = 0; ni < NI; ni++) {
          int rb = wc*WN + ni*16 + r16;
          v8bf bfv = *reinterpret_cast<const v8bf*>(
              (const char*)Bs + d*(TN*128) + rb*128 + ((ch ^ (rb & 7)) << 4));
          #pragma unroll
          for (int mi = 0; mi < MI; mi++)
            acc[d][mi][ni] = __builtin_amdgcn_mfma_f32_16x16x32_bf16(af[mi], bfv, acc[d][mi][ni], 0, 0, 0);
        }
    }
    __syncthreads();
  }

  int colb = n0 + wc*WN + r16;
  int rowb = m0 + wr*WM + (g4 << 2);
  #pragma unroll
  for (int mi = 0; mi < MI; mi++)
    #pragma unroll
    for (int ni = 0; ni < NI; ni++) {
      int col = colb + ni*16;
      if constexpr (EPI == EPI_ADASG) {
        if (z < 2) {
          float bg = (z == 0 ? f1 : f2)[col];
          bf16* o = (bf16*)outp + (long)z * sOutz;
          #pragma unroll
          for (int r = 0; r < 4; r++) {
            long idx = (long)(rowb + mi*16 + r)*768 + col;
            float gl = acc[0][mi][ni][r] + bg;
            o[idx] = (bf16)(sigf(gl) * f0[idx] + acc[1][mi][ni][r]);
          }
        } else {
          bf16* o0 = (bf16*)outp + 2*sOutz;
          bf16* o1 = (bf16*)outp + 3*sOutz;
          #pragma unroll
          for (int r = 0; r < 4; r++) {
            long idx = (long)(rowb + mi*16 + r)*768 + col;
            o0[idx] = (bf16)sigf(acc[0][mi][ni][r] + f3[col]);
            o1[idx] = (bf16)sigf(acc[1][mi][ni][r] + f4[col]);
          }
        }
      } else if constexpr (EPI == EPI_SWIGLU) {
        bf16* o = (bf16*)outp;
        #pragma unroll
        for (int r = 0; r < 4; r++) {
          long idx = (long)(rowb + mi*16 + r)*1536 + col;
          float x1 = acc[0][mi][ni][r], x2 = acc[1][mi][ni][r];
          o[idx] = (bf16)(x1 * sigf(x1) * x2);
        }
      } else if constexpr (EPI == EPI_QKVG) {
        int h = col / 48, d = col - h*48;
        if (z == 0) {
          const float qs = 0.14433756729740643f;
          bf16* qp = (bf16*)outp;
          #pragma unroll
          for (int r = 0; r < 4; r++)
            qp[(long)h*65536 + (long)(rowb + mi*16 + r)*64 + d] =
              (bf16)((acc[0][mi][ni][r] + f0[col]) * qs);
        } else if (z == 1) {
          bf16* kp = (bf16*)outp + sOutz;
          #pragma unroll
          for (int r = 0; r < 4; r++)
            kp[(long)h*65536 + (long)(rowb + mi*16 + r)*64 + d] = (bf16)acc[0][mi][ni][r];
        } else if (z == 2) {
          bf16* vT = (bf16*)outp + 2*sOutz;
          union { bf16 h4[4]; short4v s4; } u;
          #pragma unroll
          for (int r = 0; r < 4; r++) u.h4[r] = (bf16)acc[0][mi][ni][r];
          *reinterpret_cast<short4v*>(&vT[(long)h*65536 + (long)d*1024 + rowb + mi*16]) = u.s4;
        } else {
          bf16* gp = (bf16*)outp + 3*sOutz;
          #pragma unroll
          for (int r = 0; r < 4; r++)
            gp[(long)(rowb + mi*16 + r)*768 + col] = (bf16)sigf(acc[0][mi][ni][r] + f1[col]);
        }
      } else if constexpr (EPI == EPI_WO) {
        float* o = (float*)outp;
        #pragma unroll
        for (int r = 0; r < 4; r++) {
          long idx = (long)(rowb + mi*16 + r)*768 + col;
          o[idx] = (float)bb0[idx] * (acc[0][mi][ni][r] + f0[col]);
        }
      } else {  // EPI_WB: OUT = opj + sgf1*acc
        float* o = (float*)outp;
        #pragma unroll
        for (int r = 0; r < 4; r++) {
          long idx = (long)(rowb + mi*16 + r)*768 + col;
          o[idx] = f0[idx] + (float)bb0[idx] * acc[0][mi][ni][r];
        }
      }
    }
}

template<int TM, int TN, bool DUAL, int EPI>
__global__ __launch_bounds__(256) void gemm_k(
    const bf16* A, const bf16* B, long sAz, long sBz, long sBpair, int K,
    const float* f0, const float* f1, const float* f2, const float* f3,
    const float* f4, const bf16* bb0, void* outp, long sOutz)
{
  __shared__ __align__(16) bf16 As[TM*64];
  __shared__ __align__(16) bf16 Bs[(DUAL?2:1)*TN*64];
  int z = blockIdx.z;
  gemm_body<TM,TN,DUAL,EPI>(As, Bs, blockIdx.y*TM, blockIdx.x*TN, z,
      A + (long)z*sAz, B + (long)z*sBz, sBpair, K,
      f0, f1, f2, f3, f4, bb0, outp, sOutz);
}

#define ZSPLIT 5120

// ---------------------------------------------------------------- mega A
// adaLN+gates GEMM (576 blocks, first) ∥ zbias[0..ZSPLIT)
__global__ __launch_bounds__(256, 4) void k_mega_a(
    const bf16* sl1, const bf16* wGA6, const float* alnr,
    const float* bg1, const float* bg2, const float* bsL, const float* b_t,
    bf16* aln, const float* Zin, const bf16* wzT, bf16* biasb)
{
  __shared__ __align__(16) char smem[24576];
  int bid = blockIdx.x;
  if (bid < 576) {
    int z = bid / 192, rem = bid % 192;
    gemm_body<64,64,true,EPI_ADASG>((bf16*)smem, (bf16*)(smem + 8192),
        (rem/12)*64, (rem%12)*64, z,
        sl1 + (long)z*393216, wGA6 + (long)z*589824, 294912, 384,
        alnr, bg1, bg2, bsL, b_t, nullptr, aln, 786432);
  } else {
    zbias_body(bid - 576, smem, Zin, wzT, biasb);
  }
}

// ---------------------------------------------------------------- mega B
// QKVG 128x128 (192, first) ∥ SwiGLU 64x64 dual (384) ∥ zbias[ZSPLIT..16384)
__global__ __launch_bounds__(256, 3) void k_mega_b(
    const bf16* aln, const bf16* wQKVG, const float* bq, const float* bgate,
    bf16* qkv, const bf16* a2b, const bf16* wW12, bf16* bmid,
    const float* Zin, const bf16* wzT, bf16* biasb)
{
  __shared__ __align__(16) char smem[32768];
  int bid = blockIdx.x;
  if (bid < 192) {
    int z = bid / 48, rem = bid % 48;
    gemm_body<128,128,false,EPI_QKVG>((bf16*)smem, (bf16*)(smem + 16384),
        (rem/6)*128, (rem%6)*128, z,
        aln, wQKVG + (long)z*589824, 0, 768,
        bq, bgate, nullptr, nullptr, nullptr, nullptr, qkv, 1048576);
  } else if (bid < 576) {
    int rem = bid - 192;
    gemm_body<64,64,true,EPI_SWIGLU>((bf16*)smem, (bf16*)(smem + 8192),
        (rem/24)*64, (rem%24)*64, 0,
        a2b, wW12, 1179648, 768,
        nullptr, nullptr, nullptr, nullptr, nullptr, nullptr, bmid, 0);
  } else {
    zbias_body(bid - 576 + ZSPLIT, smem, Zin, wzT, biasb);
  }
}

// ---------------------------------------------------------------- flash attn
__global__ __launch_bounds__(256) void k_flash(
    const bf16* __restrict__ qp, const bf16* __restrict__ kp,
    const bf16* __restrict__ vT, const bf16* __restrict__ biasb,
    const bf16* __restrict__ gp, bf16* __restrict__ gob)
{
  __shared__ bf16 pl[4][16*72];
  int t = threadIdx.x, lane = t & 63, w = t >> 6;
  int h = blockIdx.y;
  int q0 = blockIdx.x * 64 + w * 16;
  int r16 = lane & 15, g4 = lane >> 4;
  const bf16* qb = qp + ((long)h << 16);
  const bf16* kb = kp + ((long)h << 16);
  const bf16* vb = vT + ((long)h << 16);
  const bf16* bb = biasb + ((long)h << 20) + (long)q0 * 1024;

  v8bf qa[2];
  #pragma unroll
  for (int s = 0; s < 2; s++)
    qa[s] = *reinterpret_cast<const v8bf*>(&qb[(long)(q0 + r16)*64 + s*32 + g4*8]);

  v4f oacc[4];
  #pragma unroll
  for (int nd = 0; nd < 4; nd++) oacc[nd] = (v4f){0.f, 0.f, 0.f, 0.f};
  float mrun[4], lrun[4];
  #pragma unroll
  for (int r = 0; r < 4; r++){ mrun[r] = -1e30f; lrun[r] = 0.f; }

  for (int kt = 0; kt < 16; kt++) {
    int k0 = kt * 64;
    v4f sacc[4];
    #pragma unroll
    for (int nk = 0; nk < 4; nk++) sacc[nk] = (v4f){0.f, 0.f, 0.f, 0.f};
    #pragma unroll
    for (int nk = 0; nk < 4; nk++)
      #pragma unroll
      for (int s = 0; s < 2; s++) {
        v8bf kf = *reinterpret_cast<const v8bf*>(&kb[(long)(k0 + nk*16 + r16)*64 + s*32 + g4*8]);
        sacc[nk] = __builtin_amdgcn_mfma_f32_16x16x32_bf16(qa[s], kf, sacc[nk], 0, 0, 0);
      }
    float mtile[4];
    #pragma unroll
    for (int r = 0; r < 4; r++) mtile[r] = -1e30f;
    #pragma unroll
    for (int nk = 0; nk < 4; nk++)
      #pragma unroll
      for (int r = 0; r < 4; r++) {
        float bvv = (float)bb[(long)(g4*4 + r)*1024 + k0 + nk*16 + r16];
        sacc[nk][r] += bvv;
        mtile[r] = fmaxf(mtile[r], sacc[nk][r]);
      }
    #pragma unroll
    for (int r = 0; r < 4; r++) {
      #pragma unroll
      for (int m = 1; m < 16; m <<= 1) mtile[r] = fmaxf(mtile[r], __shfl_xor(mtile[r], m));
    }
    float scl[4], rsum[4];
    #pragma unroll
    for (int r = 0; r < 4; r++) {
      float mn = fmaxf(mrun[r], mtile[r]);
      scl[r] = __expf(mrun[r] - mn);
      mrun[r] = mn;
      rsum[r] = 0.f;
    }
    bf16* plw = &pl[w][0];
    #pragma unroll
    for (int nk = 0; nk < 4; nk++)
      #pragma unroll
      for (int r = 0; r < 4; r++) {
        float p = __expf(sacc[nk][r] - mrun[r]);
        rsum[r] += p;
        plw[(g4*4 + r)*72 + nk*16 + r16] = (bf16)p;
      }
    #pragma unroll
    for (int r = 0; r < 4; r++) {
      #pragma unroll
      for (int m = 1; m < 16; m <<= 1) rsum[r] += __shfl_xor(rsum[r], m);
      lrun[r] = lrun[r]*scl[r] + rsum[r];
      #pragma unroll
      for (int nd = 0; nd < 4; nd++) oacc[nd][r] *= scl[r];
    }
    v8bf pa[2];
    #pragma unroll
    for (int s = 0; s < 2; s++)
      pa[s] = *reinterpret_cast<const v8bf*>(&plw[r16*72 + s*32 + g4*8]);
    #pragma unroll
    for (int nd = 0; nd < 4; nd++)
      #pragma unroll
      for (int s = 0; s < 2; s++) {
        v8bf vf = *reinterpret_cast<const v8bf*>(&vb[(long)(nd*16 + r16)*1024 + k0 + s*32 + g4*8]);
        oacc[nd] = __builtin_amdgcn_mfma_f32_16x16x32_bf16(pa[s], vf, oacc[nd], 0, 0, 0);
      }
  }
  #pragma unroll
  for (int r = 0; r < 4; r++) {
    int qrow = q0 + g4*4 + r;
    float invl = 1.0f / lrun[r];
    #pragma unroll
    for (int nd = 0; nd < 3; nd++) {
      long idx = (long)qrow*768 + h*48 + nd*16 + r16;
      gob[idx] = (bf16)(oacc[nd][r] * invl * (float)gp[idx]);
    }
  }
}

// ---------------------------------------------------------------- launcher
extern "C" void kernel_launch(void* const* d_in, const int* in_sizes, int n_in,
                              void* d_out, int out_size, void* d_ws, size_t ws_size,
                              hipStream_t stream)
{
  const float* A_in  = (const float*)d_in[0];
  const float* S_in  = (const float*)d_in[1];
  const float* Z_in  = (const float*)d_in[2];
  const float* g_s1  = (const float*)d_in[3];
  const float* Wg1   = (const float*)d_in[4];
  const float* bg1   = (const float*)d_in[5];
  const float* Wadd1 = (const float*)d_in[6];
  const float* g_z   = (const float*)d_in[7];
  const float* Wz    = (const float*)d_in[8];
  const float* Wq    = (const float*)d_in[9];
  const float* bq    = (const float*)d_in[10];
  const float* Wk    = (const float*)d_in[11];
  const float* Wv    = (const float*)d_in[12];
  const float* Wgate = (const float*)d_in[13];
  const float* bgate = (const float*)d_in[14];
  const float* Wo    = (const float*)d_in[15];
  const float* bo    = (const float*)d_in[16];
  const float* WsL   = (const float*)d_in[17];
  const float* bsL   = (const float*)d_in[18];
  const float* g_s2  = (const float*)d_in[19];
  const float* Wg2   = (const float*)d_in[20];
  const float* bg2   = (const float*)d_in[21];
  const float* Wadd2 = (const float*)d_in[22];
  const float* W1    = (const float*)d_in[23];
  const float* W2    = (const float*)d_in[24];
  const float* Wb    = (const float*)d_in[25];
  const float* WsT   = (const float*)d_in[26];
  const float* b_t   = (const float*)d_in[27];
  float* OUT = (float*)d_out;

  char* ws = (char*)d_ws;
  size_t off = 0;
  auto alloc = [&](size_t bytes) -> void* {
    void* p = ws + off; off += (bytes + 255) & ~(size_t)255; return p; };

  bf16*  wGA6  = (bf16*) alloc(6ul*294912*2);   // Wg1T,Wadd1T,Wg2T,Wadd2T,WsLT,WsTT
  bf16*  wQKVG = (bf16*) alloc(4ul*589824*2);   // WqT,WkT,WvT,WgateT
  bf16*  wWoT  = (bf16*) alloc(589824ul*2);
  bf16*  wW12  = (bf16*) alloc(2ul*1179648*2);  // W1T, W2T
  bf16*  wWbT  = (bf16*) alloc(1179648ul*2);
  bf16*  wzT   = (bf16*) alloc(2048ul*2);       // [16][128] gz-folded
  bf16*  sl1   = (bf16*) alloc(393216ul*2);     // sl1,sl2,sbf contiguous
  bf16*  sl2   = (bf16*) alloc(393216ul*2);
  bf16*  sbf   = (bf16*) alloc(393216ul*2);
  float* alnr  = (float*)alloc(786432ul*4);
  bf16*  aln   = (bf16*) alloc(786432ul*2);     // aln,a2b,sgf0,sgf1 contiguous
  bf16*  a2b   = (bf16*) alloc(786432ul*2);
  bf16*  sgf   = (bf16*) alloc(2ul*786432*2);
  bf16*  qkv   = (bf16*) alloc((3ul*1048576 + 786432)*2);  // qp,kp,vT,gp
  bf16*  biasb = (bf16*) alloc(16777216ul*2);
  bf16*  gob   = (bf16*) alloc(786432ul*2);
  float* opj   = (float*)alloc(786432ul*4);
  bf16*  bmid  = (bf16*) alloc(1572864ul*2);

  WTab tab;
  auto setw = [&](int i, const float* src, bf16* dst, int K, int N){
    tab.src[i] = src; tab.dst[i] = dst; tab.K[i] = K; tab.N[i] = N; };
  setw(0,  Wg1,   wGA6,             384,  768);
  setw(1,  Wadd1, wGA6 + 294912,    384,  768);
  setw(2,  Wg2,   wGA6 + 589824,    384,  768);
  setw(3,  Wadd2, wGA6 + 884736,    384,  768);
  setw(4,  WsL,   wGA6 + 1179648,   384,  768);
  setw(5,  WsT,   wGA6 + 1474560,   384,  768);
  setw(6,  Wq,    wQKVG,            768,  768);
  setw(7,  Wk,    wQKVG + 589824,   768,  768);
  setw(8,  Wv,    wQKVG + 2*589824, 768,  768);
  setw(9,  Wgate, wQKVG + 3*589824, 768,  768);
  setw(10, Wo,    wWoT,             768,  768);
  setw(11, W1,    wW12,             768, 1536);
  setw(12, W2,    wW12 + 1179648,   768, 1536);
  setw(13, Wb,    wWbT,            1536,  768);
  int boff = 0;
  for (int i = 0; i < 14; i++){ tab.boff[i] = boff; boff += (tab.K[i]/32)*(tab.N[i]/32); }

  (void)hipMemsetAsync(qkv, 0, 3ul*1048576*2, stream);  // zero q,k,vT pads

  // prepw + prepz + ln_a + ln_s in one launch
  k_prep<<<boff + 8 + 1024 + 512, 256, 0, stream>>>(
      tab, boff, Wz, g_z, wzT, A_in, alnr, S_in, g_s1, g_s2, sl1, sl2, sbf);

  // adaLN+gates ∥ zbias[0..ZSPLIT)
  k_mega_a<<<576 + ZSPLIT, 256, 0, stream>>>(
      sl1, wGA6, alnr, bg1, bg2, bsL, b_t, aln, Z_in, wzT, biasb);

  // QKVG(128²) ∥ SwiGLU ∥ zbias[ZSPLIT..16384)
  k_mega_b<<<576 + (16384 - ZSPLIT), 256, 0, stream>>>(
      aln, wQKVG, bq, bgate, qkv, a2b, wW12, bmid, Z_in, wzT, biasb);

  // fused attention: scores+bias -> online softmax -> PV -> gate
  k_flash<<<dim3(16,16), 256, 0, stream>>>(
      qkv, qkv + 1048576, qkv + 2097152, biasb, qkv + 3145728, gob);

  // opj = sgf0 * (gob @ Wo^T + bo)
  gemm_k<64,64,false,EPI_WO><<<dim3(12,16,1), 256, 0, stream>>>(
      gob, wWoT, 0, 0, 0, 768,
      bo, nullptr, nullptr, nullptr, nullptr, sgf, opj, 0);

  // OUT = opj + sgf1 * (bmid @ Wb^T)
  gemm_k<64,64,false,EPI_WB><<<dim3(12,16,1), 256, 0, stream>>>(
      bmid, wWbT, 0, 0, 0, 1536,
      opj, nullptr, nullptr, nullptr, nullptr, sgf + 786432, OUT, 0);
}